// Round 1
// baseline (288.068 us; speedup 1.0000x reference)
//
#include <hip/hip_runtime.h>
#include <math.h>

#define NB 16
#define CI 64
#define CO 32
#define IH 128
#define IW 128
#define OH 256
#define OW 256
#define ROWS_PER_BLOCK 4
#define NG (OH / ROWS_PER_BLOCK)   // 64 row-groups

// k0: transpose weights w[ci][co][kh][kw] -> wt[kh][kw][ci][co] (co contiguous
// so the main kernel's uniform weight reads become s_load_dwordx16).
__global__ void transpose_w(const float* __restrict__ w, float* __restrict__ wt) {
    int i = blockIdx.x * 256 + threadIdx.x;   // 0 .. 32767
    if (i >= CI * CO * 16) return;
    int kw = i & 3;
    int kh = (i >> 2) & 3;
    int co = (i >> 4) & 31;
    int ci = i >> 9;
    wt[((kh * 4 + kw) * CI + ci) * CO + co] = w[i];
}

// k1: each block = (n, row-group g, ow-parity pw). 128 threads, one ow each
// (ow = 2*t + pw). Per row: accumulate 32 channel values (conv_b-seeded),
// take min, add into running height-partial. Weights are block/loop-uniform
// -> scalar loads. x loads are per-lane coalesced global loads (L1-reused).
__global__ __launch_bounds__(128) void convt_min_rows(
    const float* __restrict__ x, const float* __restrict__ wt,
    const float* __restrict__ conv_b, float* __restrict__ partial)
{
    int b  = blockIdx.x;          // ((n*NG + g)*2 + pw)
    int pw = b & 1;
    int g  = (b >> 1) % NG;
    int n  = (b >> 1) / NG;
    int t  = threadIdx.x;         // 0..127
    int ow = 2 * t + pw;

    // width taps: iwA pairs kwA, iwB = iwA-1 pairs kwB = kwA+2
    int iwA = pw ? (t + 1) : t;
    int iwB = iwA - 1;
    float mA_w = (iwA >= 0 && iwA < IW) ? 1.f : 0.f;
    float mB_w = (iwB >= 0 && iwB < IW) ? 1.f : 0.f;
    int iwAc = min(max(iwA, 0), IW - 1);
    int iwBc = min(max(iwB, 0), IW - 1);
    int kwA = pw ? 0 : 1;         // block-uniform
    int kwB = kwA + 2;

    const float* xn = x + (size_t)n * CI * IH * IW;

    float rsum = 0.f;
    for (int r = 0; r < ROWS_PER_BLOCK; ++r) {
        int oh  = g * ROWS_PER_BLOCK + r;
        int khA = (oh & 1) ? 0 : 1;     // loop-uniform
        int khB = khA + 2;
        int ihA = (oh + (oh & 1)) >> 1; // ceil(oh/2)
        int ihB = ihA - 1;
        float mA_h = (ihA < IH) ? 1.f : 0.f;  // ihA >= 0 always
        float mB_h = (ihB >= 0) ? 1.f : 0.f;
        int rowA = min(ihA, IH - 1) * IW;
        int rowB = max(ihB, 0) * IW;

        float m00 = mA_h * mA_w, m01 = mA_h * mB_w;
        float m10 = mB_h * mA_w, m11 = mB_h * mB_w;

        const float* wAA = wt + (khA * 4 + kwA) * CI * CO;
        const float* wAB = wt + (khA * 4 + kwB) * CI * CO;
        const float* wBA = wt + (khB * 4 + kwA) * CI * CO;
        const float* wBB = wt + (khB * 4 + kwB) * CI * CO;

        float acc[CO];
        #pragma unroll
        for (int c = 0; c < CO; ++c) acc[c] = conv_b[c];

        for (int ci = 0; ci < CI; ++ci) {
            const float* px = xn + ci * IH * IW;
            float xAA = px[rowA + iwAc] * m00;
            float xAB = px[rowA + iwBc] * m01;
            float xBA = px[rowB + iwAc] * m10;
            float xBB = px[rowB + iwBc] * m11;
            const float* w0 = wAA + ci * CO;
            const float* w1 = wAB + ci * CO;
            const float* w2 = wBA + ci * CO;
            const float* w3 = wBB + ci * CO;
            #pragma unroll
            for (int c = 0; c < CO; ++c) {
                float a = acc[c];
                a = fmaf(xAA, w0[c], a);
                a = fmaf(xAB, w1[c], a);
                a = fmaf(xBA, w2[c], a);
                a = fmaf(xBB, w3[c], a);
                acc[c] = a;
            }
        }
        float mn = acc[0];
        #pragma unroll
        for (int c = 1; c < CO; ++c) mn = fminf(mn, acc[c]);
        rsum += mn;
    }
    partial[((size_t)n * NG + g) * OW + ow] = rsum;
}

// k2: sum the NG height-partials per (n, ow), apply tanh-GELU + bias.
__global__ void finalize(const float* __restrict__ partial,
                         const float* __restrict__ bias,
                         float* __restrict__ out)
{
    int i = blockIdx.x * 256 + threadIdx.x;  // 0 .. 4095
    int n = i >> 8;
    int ow = i & 255;
    float s = 0.f;
    #pragma unroll 4
    for (int g = 0; g < NG; ++g) s += partial[((size_t)n * NG + g) * OW + ow];
    float u = 0.7978845608028654f * (s + 0.044715f * s * s * s);
    float gl = 0.5f * s * (1.f + tanhf(u));
    out[i] = gl + bias[0];
}

extern "C" void kernel_launch(void* const* d_in, const int* in_sizes, int n_in,
                              void* d_out, int out_size, void* d_ws, size_t ws_size,
                              hipStream_t stream) {
    const float* x      = (const float*)d_in[0];   // [16,64,128,128]
    const float* w      = (const float*)d_in[1];   // [64,32,4,4]
    const float* conv_b = (const float*)d_in[2];   // [32]
    const float* bias   = (const float*)d_in[3];   // [1]
    float* out = (float*)d_out;                    // 16*256

    float* wt      = (float*)d_ws;                 // 32768 floats
    float* partial = wt + CI * CO * 16;            // 16*NG*256 = 262144 floats

    hipLaunchKernelGGL(transpose_w, dim3(128), dim3(256), 0, stream, w, wt);
    hipLaunchKernelGGL(convt_min_rows, dim3(NB * NG * 2), dim3(128), 0, stream,
                       x, wt, conv_b, partial);
    hipLaunchKernelGGL(finalize, dim3(NB), dim3(256), 0, stream,
                       partial, bias, out);
}

// Round 2
// 147.497 us; speedup vs baseline: 1.9530x; 1.9530x over previous
//
#include <hip/hip_runtime.h>
#include <math.h>

typedef __attribute__((ext_vector_type(8))) short short8;
typedef __attribute__((ext_vector_type(16))) float f32x16;

#define XS_STRIDE 72   // shorts per (row,col) cell: 64 ci + 8 pad -> 144 B, 16B-aligned

__device__ __forceinline__ short f2bf(float f) {
    union { float f; unsigned u; } v; v.f = f;
    unsigned r = (v.u + 0x7FFFu + ((v.u >> 16) & 1u)) >> 16;
    return (short)r;
}

// Build weight A-fragments in MFMA 32x32x16 A-operand layout, per parity p.
// wfrag[p][q][lane][j] : p=ph*2+pw, q = tap*4 + ci_block, lane&31=co,
// ci = (q&3)*16 + (lane>>5)*8 + j, tap t=(a,b): kh=2a+1-ph, kw=2b+1-pw.
__global__ void build_wfrag(const float* __restrict__ w, short* __restrict__ wfrag) {
    int idx = blockIdx.x * 256 + threadIdx.x;   // 0 .. 32767
    int j    = idx & 7;
    int lane = (idx >> 3) & 63;
    int q    = (idx >> 9) & 15;
    int p    = idx >> 13;
    int co = lane & 31, half = lane >> 5;
    int ci = (q & 3) * 16 + half * 8 + j;
    int t = q >> 2, a = t >> 1, b = t & 1;
    int ph = p >> 1, pw = p & 1;
    int kh = 2 * a + 1 - ph, kw = 2 * b + 1 - pw;
    wfrag[idx] = f2bf(w[((ci * 32 + co) * 4 + kh) * 4 + kw]);
}

// Block = (n, input row i, col half jh). Stages x[i-1..i+1] as bf16 to LDS,
// 4 waves = 4 output parities, each runs GEMM co(32) x pixels(32) x K(256)
// with mfma_f32_32x32x16_bf16, then min over co, ph-pair sum -> partial[n][i][ow].
__global__ __launch_bounds__(256, 4) void convt_mfma(
    const float* __restrict__ x, const short* __restrict__ wfrag,
    const float* __restrict__ conv_b, float* __restrict__ partial)
{
    __shared__ short xs[3][66][XS_STRIDE];   // [row][col(-1..64)][ci], 28.5 KB
    __shared__ float minbuf[4][64];

    int blk = blockIdx.x;
    int jh = blk & 1;
    int i  = (blk >> 1) & 127;
    int n  = blk >> 8;
    int t  = threadIdx.x;

    // ---- stage x rows i-1..i+1, global cols jh*64-1 .. jh*64+64 (zero pad) ----
    {
        int col  = t & 63;
        int cih  = (t >> 6) * 4;            // 4 consecutive ci per thread
        int gcol = jh * 64 + col;
        for (int r = 0; r < 3; ++r) {
            int gi = i - 1 + r;
            bool rowok = (unsigned)gi < 128u;
            int gic = rowok ? gi : 0;
            for (int g = 0; g < 4; ++g) {
                int ci = g * 16 + cih;
                const float* px = x + (((size_t)(n * 64 + ci) * 128 + gic) * 128 + gcol);
                float v0 = rowok ? px[0]     : 0.f;
                float v1 = rowok ? px[16384] : 0.f;   // +1 ci plane
                float v2 = rowok ? px[32768] : 0.f;
                float v3 = rowok ? px[49152] : 0.f;
                union { short s[4]; unsigned long long u; } pk;
                pk.s[0] = f2bf(v0); pk.s[1] = f2bf(v1);
                pk.s[2] = f2bf(v2); pk.s[3] = f2bf(v3);
                *(unsigned long long*)&xs[r][col + 1][ci] = pk.u;
            }
        }
        if (t < 192) {   // halo cols: local 0 (g=-1) and 65 (g=+64)
            int r = t >> 6, ci = t & 63, gi = i - 1 + r;
            for (int side = 0; side < 2; ++side) {
                int gc = jh * 64 + (side ? 64 : -1);
                float v = ((unsigned)gi < 128u && (unsigned)gc < 128u)
                        ? x[((size_t)(n * 64 + ci) * 128 + gi) * 128 + gc] : 0.f;
                xs[r][side ? 65 : 0][ci] = f2bf(v);
            }
        }
    }
    __syncthreads();

    int wv = t >> 6, lane = t & 63;        // wave = parity (ph,pw)
    int ph = wv >> 1, pw = wv & 1;
    int ln = lane & 31, half = lane >> 5;

    // A fragments: 16 chunks x 8 bf16/lane, resident in VGPRs
    short8 af[16];
    const short8* wf = (const short8*)(wfrag + wv * 8192);
    #pragma unroll
    for (int q = 0; q < 16; ++q) af[q] = wf[q * 64 + lane];

    // conv_b seed in C/D layout: row(co) = (reg&3) + 8*(reg>>2) + 4*half (m74/m101)
    float cb[16];
    #pragma unroll
    for (int reg = 0; reg < 16; ++reg) {
        int co = (reg & 3) + 8 * (reg >> 2) + 4 * half;
        cb[reg] = conv_b[co];
    }

    for (int j0 = 0; j0 < 64; j0 += 32) {
        f32x16 acc;
        #pragma unroll
        for (int reg = 0; reg < 16; ++reg) acc[reg] = cb[reg];
        #pragma unroll
        for (int q = 0; q < 16; ++q) {
            int tq = q >> 2, a = tq >> 1, b = tq & 1;
            int ridx = 1 + ph - a;                    // row i + dh, dh = ph - a
            int colp = j0 + ln + (pw - b) + 1;        // col j + dw, dw = pw - b
            int ci0  = (q & 3) * 16 + half * 8;
            const short8* bp = (const short8*)&xs[ridx][colp][ci0];  // ds_read_b128
            acc = __builtin_amdgcn_mfma_f32_32x32x16_bf16(af[q], *bp, acc, 0, 0, 0);
        }
        float mn = acc[0];
        #pragma unroll
        for (int reg = 1; reg < 16; ++reg) mn = fminf(mn, acc[reg]);
        mn = fminf(mn, __shfl_xor(mn, 32, 64));       // fold co halves
        if (half == 0) minbuf[wv][j0 + ln] = mn;
    }
    __syncthreads();

    // ph-pair sum -> unique-writer partial[n][i][ow]
    if (t < 128) {
        int pw2 = t >> 6, jl = t & 63;
        float v = minbuf[pw2][jl] + minbuf[2 + pw2][jl];   // ph=0 + ph=1
        int ow = ((jh * 64 + jl) << 1) | pw2;
        partial[((size_t)(n * 128) + i) * 256 + ow] = v;
    }
}

// Sum 128 row-partials per (n,ow), tanh-GELU + bias.
__global__ void finalize(const float* __restrict__ partial,
                         const float* __restrict__ bias, float* __restrict__ out)
{
    int idx = blockIdx.x * 256 + threadIdx.x;  // 0..4095
    int n = idx >> 8, ow = idx & 255;
    float s = 0.f;
    #pragma unroll 4
    for (int i = 0; i < 128; ++i) s += partial[((n << 7) + i) * 256 + ow];
    float u = 0.7978845608028654f * (s + 0.044715f * s * s * s);
    out[idx] = 0.5f * s * (1.f + tanhf(u)) + bias[0];
}

extern "C" void kernel_launch(void* const* d_in, const int* in_sizes, int n_in,
                              void* d_out, int out_size, void* d_ws, size_t ws_size,
                              hipStream_t stream) {
    const float* x      = (const float*)d_in[0];   // [16,64,128,128]
    const float* w      = (const float*)d_in[1];   // [64,32,4,4]
    const float* conv_b = (const float*)d_in[2];   // [32]
    const float* bias   = (const float*)d_in[3];   // [1]
    float* out = (float*)d_out;                    // 16*256

    short* wfrag   = (short*)d_ws;                         // 32768 shorts = 64 KB
    float* partial = (float*)((char*)d_ws + 65536);        // 16*128*256 fp32 = 2 MB

    hipLaunchKernelGGL(build_wfrag, dim3(128), dim3(256), 0, stream, w, wfrag);
    hipLaunchKernelGGL(convt_mfma, dim3(16 * 128 * 2), dim3(256), 0, stream,
                       x, wfrag, conv_b, partial);
    hipLaunchKernelGGL(finalize, dim3(16), dim3(256), 0, stream,
                       partial, bias, out);
}

// Round 3
// 135.461 us; speedup vs baseline: 2.1266x; 1.0889x over previous
//
#include <hip/hip_runtime.h>
#include <math.h>

typedef __attribute__((ext_vector_type(8))) short short8;
typedef __attribute__((ext_vector_type(16))) float f32x16;

#define XS_STRIDE 72   // shorts per (row,col) cell: 64 ci + 8 pad -> 144 B, 16B-aligned

__device__ __forceinline__ short f2bf(float f) {
    union { float f; unsigned u; } v; v.f = f;
    unsigned r = (v.u + 0x7FFFu + ((v.u >> 16) & 1u)) >> 16;
    return (short)r;
}

// Zero the 4096-float accumulator (ws is poisoned 0xAA before every call).
__global__ void zero_acc(float* __restrict__ acc) {
    acc[blockIdx.x * 256 + threadIdx.x] = 0.f;
}

// Build weight A-fragments in MFMA 32x32x16 A-operand layout, per parity p.
// wfrag[p][q][lane][j] : p=ph*2+pw, q = tap*4 + ci_block, lane&31=co,
// ci = (q&3)*16 + (lane>>5)*8 + j, tap t=(a,b): kh=2a+1-ph, kw=2b+1-pw.
__global__ void build_wfrag(const float* __restrict__ w, short* __restrict__ wfrag) {
    int idx = blockIdx.x * 256 + threadIdx.x;   // 0 .. 32767
    int j    = idx & 7;
    int lane = (idx >> 3) & 63;
    int q    = (idx >> 9) & 15;
    int p    = idx >> 13;
    int co = lane & 31, half = lane >> 5;
    int ci = (q & 3) * 16 + half * 8 + j;
    int t = q >> 2, a = t >> 1, b = t & 1;
    int ph = p >> 1, pw = p & 1;
    int kh = 2 * a + 1 - ph, kw = 2 * b + 1 - pw;
    wfrag[idx] = f2bf(w[((ci * 32 + co) * 4 + kh) * 4 + kw]);
}

// Block = (n, input row pair i0..i0+1, col half jh). Stages x rows i0-1..i0+2
// as bf16 to LDS (4 rows -> 2x reuse vs 3 rows -> 1), 4 waves = 4 output
// parities, each runs GEMM co(32) x pixels(32) x K(256) per row-pair with
// mfma_f32_32x32x16_bf16, min over co, ph-pair sum -> atomicAdd acc[n][ow].
__global__ __launch_bounds__(256, 4) void convt_mfma(
    const float* __restrict__ x, const short* __restrict__ wfrag,
    const float* __restrict__ conv_b, float* __restrict__ acc4096)
{
    __shared__ short xs[4][66][XS_STRIDE];   // [row][col(-1..64)][ci], 38 KB
    __shared__ float minbuf[2][4][64];       // [rp][parity][col]

    int blk = blockIdx.x;
    int jh = blk & 1;
    int i0 = ((blk >> 1) & 63) * 2;
    int n  = blk >> 7;
    int t  = threadIdx.x;

    // ---- stage x rows i0-1..i0+2, global cols jh*64-1 .. jh*64+64 (zero pad) ----
    {
        int col  = t & 63;
        int cih  = (t >> 6) * 4;            // 4 consecutive ci per thread
        int gcol = jh * 64 + col;
        for (int r = 0; r < 4; ++r) {
            int gi = i0 - 1 + r;
            bool rowok = (unsigned)gi < 128u;
            int gic = rowok ? gi : 0;
            for (int g = 0; g < 4; ++g) {
                int ci = g * 16 + cih;
                const float* px = x + (((size_t)(n * 64 + ci) * 128 + gic) * 128 + gcol);
                float v0 = rowok ? px[0]     : 0.f;
                float v1 = rowok ? px[16384] : 0.f;   // +1 ci plane
                float v2 = rowok ? px[32768] : 0.f;
                float v3 = rowok ? px[49152] : 0.f;
                union { short s[4]; unsigned long long u; } pk;
                pk.s[0] = f2bf(v0); pk.s[1] = f2bf(v1);
                pk.s[2] = f2bf(v2); pk.s[3] = f2bf(v3);
                *(unsigned long long*)&xs[r][col + 1][ci] = pk.u;
            }
        }
        {   // halo cols: local 0 (g=-1) and 65 (g=+64), 4 rows x 64 ci
            int r = t >> 6, ci = t & 63, gi = i0 - 1 + r;
            for (int side = 0; side < 2; ++side) {
                int gc = jh * 64 + (side ? 64 : -1);
                float v = ((unsigned)gi < 128u && (unsigned)gc < 128u)
                        ? x[((size_t)(n * 64 + ci) * 128 + gi) * 128 + gc] : 0.f;
                xs[r][side ? 65 : 0][ci] = f2bf(v);
            }
        }
    }
    __syncthreads();

    int wv = t >> 6, lane = t & 63;        // wave = parity (ph,pw)
    int ph = wv >> 1, pw = wv & 1;
    int ln = lane & 31, half = lane >> 5;

    // A fragments: 16 chunks x 8 bf16/lane, resident in VGPRs
    short8 af[16];
    const short8* wf = (const short8*)(wfrag + wv * 8192);
    #pragma unroll
    for (int q = 0; q < 16; ++q) af[q] = wf[q * 64 + lane];

    // conv_b seed in C/D layout: row(co) = (reg&3) + 8*(reg>>2) + 4*half (m74/m101)
    float cb[16];
    #pragma unroll
    for (int reg = 0; reg < 16; ++reg) {
        int co = (reg & 3) + 8 * (reg >> 2) + 4 * half;
        cb[reg] = conv_b[co];
    }

    #pragma unroll
    for (int rp = 0; rp < 2; ++rp) {
        for (int j0 = 0; j0 < 64; j0 += 32) {
            f32x16 acc;
            #pragma unroll
            for (int reg = 0; reg < 16; ++reg) acc[reg] = cb[reg];
            #pragma unroll
            for (int q = 0; q < 16; ++q) {
                int tq = q >> 2, a = tq >> 1, b = tq & 1;
                int ridx = rp + 1 + ph - a;               // row (i0+rp) + dh
                int colp = j0 + ln + (pw - b) + 1;        // col j + dw
                int ci0  = (q & 3) * 16 + half * 8;
                const short8* bp = (const short8*)&xs[ridx][colp][ci0];  // ds_read_b128
                acc = __builtin_amdgcn_mfma_f32_32x32x16_bf16(af[q], *bp, acc, 0, 0, 0);
            }
            float mn = acc[0];
            #pragma unroll
            for (int reg = 1; reg < 16; ++reg) mn = fminf(mn, acc[reg]);
            mn = fminf(mn, __shfl_xor(mn, 32, 64));       // fold co halves
            if (half == 0) minbuf[rp][wv][j0 + ln] = mn;
        }
    }
    __syncthreads();

    // ph-pair sum -> atomicAdd into acc4096[n][ow]; all 256 threads, 1 atomic each
    {
        int rp  = t >> 7;
        int pw2 = (t >> 6) & 1;
        int jl  = t & 63;
        float v = minbuf[rp][pw2][jl] + minbuf[rp][2 + pw2][jl];   // ph=0 + ph=1
        int ow = ((jh * 64 + jl) << 1) | pw2;
        atomicAdd(&acc4096[n * 256 + ow], v);
    }
}

// GELU(tanh) + bias on the 4096 accumulated sums.
__global__ void finalize(const float* __restrict__ acc4096,
                         const float* __restrict__ bias, float* __restrict__ out)
{
    int idx = blockIdx.x * 256 + threadIdx.x;  // 0..4095
    float s = acc4096[idx];
    float u = 0.7978845608028654f * (s + 0.044715f * s * s * s);
    out[idx] = 0.5f * s * (1.f + tanhf(u)) + bias[0];
}

extern "C" void kernel_launch(void* const* d_in, const int* in_sizes, int n_in,
                              void* d_out, int out_size, void* d_ws, size_t ws_size,
                              hipStream_t stream) {
    const float* x      = (const float*)d_in[0];   // [16,64,128,128]
    const float* w      = (const float*)d_in[1];   // [64,32,4,4]
    const float* conv_b = (const float*)d_in[2];   // [32]
    const float* bias   = (const float*)d_in[3];   // [1]
    float* out = (float*)d_out;                    // 16*256

    float* acc   = (float*)d_ws;                         // 4096 floats = 16 KB
    short* wfrag = (short*)((char*)d_ws + 16384);        // 32768 shorts = 64 KB

    hipLaunchKernelGGL(zero_acc, dim3(16), dim3(256), 0, stream, acc);
    hipLaunchKernelGGL(build_wfrag, dim3(128), dim3(256), 0, stream, w, wfrag);
    hipLaunchKernelGGL(convt_mfma, dim3(16 * 64 * 2), dim3(256), 0, stream,
                       x, wfrag, conv_b, acc);
    hipLaunchKernelGGL(finalize, dim3(16), dim3(256), 0, stream,
                       acc, bias, out);
}